// Round 4
// baseline (6389.056 us; speedup 1.0000x reference)
//
#include <hip/hip_runtime.h>
#include <hip/hip_bf16.h>
#include <hip/hip_fp16.h>
#include <stdint.h>

#define BB 32
#define TT 2048
#define HH 512
#define MM (BB*TT)   // 65536 rows

typedef __attribute__((ext_vector_type(8))) short bf16x8;
typedef __attribute__((ext_vector_type(4))) float f32x4;
typedef __attribute__((ext_vector_type(2))) float f32x2;
typedef __attribute__((ext_vector_type(4))) unsigned short us4;
typedef __attribute__((ext_vector_type(8))) unsigned short us8;
typedef unsigned long long u64;

__device__ __forceinline__ unsigned short f2bf(float f) {
  __hip_bfloat16 h = __float2bfloat16(f);
  return *reinterpret_cast<unsigned short*>(&h);
}
__device__ __forceinline__ float bf2f(unsigned short u) {
  return __uint_as_float(((unsigned int)u) << 16);
}

// lgkm-only workgroup barrier: does NOT drain vmcnt (keeps prefetch/stores in flight)
__device__ __forceinline__ void wg_barrier_lgkm() {
  asm volatile("s_waitcnt lgkmcnt(0)\n\ts_barrier" ::: "memory");
}

// fast sigmoid / tanh (v_exp + v_rcp; |err| ~1e-6, fine vs 0.02 budget)
__device__ __forceinline__ float fast_sigmoid(float x) {
  float e = __expf(-x);                       // large +x -> e->0 -> 1; large -x -> inf -> rcp -> 0
  return __builtin_amdgcn_rcpf(1.f + e);
}
__device__ __forceinline__ float fast_tanh(float x) {
  float xc = fminf(fmaxf(x, -15.f), 15.f);    // avoid inf/inf
  float e2 = __expf(2.f * xc);
  return (e2 - 1.f) * __builtin_amdgcn_rcpf(e2 + 1.f);
}

// ---------------------------------------------------------------------------
// Weight convert + transpose: W[k][n] fp32 -> WT[n][k] bf16 (and hi/lo for wc_i)
// ---------------------------------------------------------------------------
__global__ void wconv_kernel(const float* __restrict__ wu, const float* __restrict__ wr,
                             const float* __restrict__ wc,
                             unsigned short* __restrict__ wuT, unsigned short* __restrict__ wrT,
                             unsigned short* __restrict__ wcTh, unsigned short* __restrict__ wcTl) {
  int idx = blockIdx.x * 256 + threadIdx.x;      // 0..262143
  int n = idx >> 9, k = idx & 511;
  int src = k * HH + n;
  wuT[idx] = f2bf(wu[src]);
  wrT[idx] = f2bf(wr[src]);
  float v = wc[src];
  unsigned short hi = f2bf(v);
  wcTh[idx] = hi;
  wcTl[idx] = f2bf(v - bf2f(hi));
}

// ---------------------------------------------------------------------------
// Projection GEMM.  A = x (M x 512 fp32, converted to bf16 tiles on the fly),
// B*T stored transposed [N][K] bf16.  BM=128 BN=64 BK=64, 256 thr / 4 waves.
// MODE 0: out = pack(f16(A@B0 + bias0), f16(A@B1 + bias1)) as u32 -> d_out
// MODE 1: out = f16(Ah@B0h + Ah@B0l + Al@B0h + bias0)             -> ws (c_x)
// ---------------------------------------------------------------------------
template<int MODE>
__global__ __launch_bounds__(256) void proj_gemm(
    const float* __restrict__ X,
    const unsigned short* __restrict__ B0T,
    const unsigned short* __restrict__ B1T,
    const float* __restrict__ bias0,
    const float* __restrict__ bias1,
    void* __restrict__ outp) {
  __shared__ __attribute__((aligned(16))) unsigned short Ah[128][72];
  __shared__ __attribute__((aligned(16))) unsigned short Al[128][72];
  __shared__ __attribute__((aligned(16))) unsigned short Bs0[64][72];
  __shared__ __attribute__((aligned(16))) unsigned short Bs1[64][72];
  const int tid = threadIdx.x;
  const int w = tid >> 6, l = tid & 63;
  const int lr = l & 15, lk = l >> 4;
  const int rowBase = blockIdx.x * 128;
  const int colBase = blockIdx.y * 64;

  f32x4 acc0[2][4], acc1[2][4];
  const f32x4 zero = {0.f, 0.f, 0.f, 0.f};
  #pragma unroll
  for (int m = 0; m < 2; ++m)
    #pragma unroll
    for (int n = 0; n < 4; ++n) { acc0[m][n] = zero; acc1[m][n] = zero; }

  for (int kt = 0; kt < 8; ++kt) {
    // stage A (fp32 -> bf16, hi/lo for MODE 1)
    #pragma unroll
    for (int i = 0; i < 8; ++i) {
      int idx = tid + 256 * i;
      int r = idx >> 4, c4 = idx & 15;
      float4 v = *reinterpret_cast<const float4*>(
          X + (size_t)(rowBase + r) * HH + kt * 64 + c4 * 4);
      us4 hv;
      hv.x = f2bf(v.x); hv.y = f2bf(v.y); hv.z = f2bf(v.z); hv.w = f2bf(v.w);
      *reinterpret_cast<us4*>(&Ah[r][c4 * 4]) = hv;
      if (MODE == 1) {
        us4 lv;
        lv.x = f2bf(v.x - bf2f(hv.x)); lv.y = f2bf(v.y - bf2f(hv.y));
        lv.z = f2bf(v.z - bf2f(hv.z)); lv.w = f2bf(v.w - bf2f(hv.w));
        *reinterpret_cast<us4*>(&Al[r][c4 * 4]) = lv;
      }
    }
    // stage B (already bf16, [n][k] layout)
    #pragma unroll
    for (int i = 0; i < 2; ++i) {
      int idx = tid + 256 * i;
      int n = idx >> 3, k8 = idx & 7;
      const size_t go = (size_t)(colBase + n) * HH + kt * 64 + k8 * 8;
      *reinterpret_cast<us8*>(&Bs0[n][k8 * 8]) = *reinterpret_cast<const us8*>(B0T + go);
      *reinterpret_cast<us8*>(&Bs1[n][k8 * 8]) = *reinterpret_cast<const us8*>(B1T + go);
    }
    __syncthreads();
    #pragma unroll
    for (int ks = 0; ks < 2; ++ks) {
      const int k0 = ks * 32 + lk * 8;
      bf16x8 a[2], b0[4], b1[4];
      #pragma unroll
      for (int m = 0; m < 2; ++m)
        a[m] = *reinterpret_cast<const bf16x8*>(&Ah[32 * w + 16 * m + lr][k0]);
      #pragma unroll
      for (int n = 0; n < 4; ++n) {
        b0[n] = *reinterpret_cast<const bf16x8*>(&Bs0[16 * n + lr][k0]);
        b1[n] = *reinterpret_cast<const bf16x8*>(&Bs1[16 * n + lr][k0]);
      }
      if (MODE == 1) {
        bf16x8 al[2];
        #pragma unroll
        for (int m = 0; m < 2; ++m)
          al[m] = *reinterpret_cast<const bf16x8*>(&Al[32 * w + 16 * m + lr][k0]);
        #pragma unroll
        for (int m = 0; m < 2; ++m)
          #pragma unroll
          for (int n = 0; n < 4; ++n) {
            acc0[m][n] = __builtin_amdgcn_mfma_f32_16x16x32_bf16(a[m],  b0[n], acc0[m][n], 0, 0, 0);
            acc0[m][n] = __builtin_amdgcn_mfma_f32_16x16x32_bf16(a[m],  b1[n], acc0[m][n], 0, 0, 0);
            acc0[m][n] = __builtin_amdgcn_mfma_f32_16x16x32_bf16(al[m], b0[n], acc0[m][n], 0, 0, 0);
          }
      } else {
        #pragma unroll
        for (int m = 0; m < 2; ++m)
          #pragma unroll
          for (int n = 0; n < 4; ++n) {
            acc0[m][n] = __builtin_amdgcn_mfma_f32_16x16x32_bf16(a[m], b0[n], acc0[m][n], 0, 0, 0);
            acc1[m][n] = __builtin_amdgcn_mfma_f32_16x16x32_bf16(a[m], b1[n], acc1[m][n], 0, 0, 0);
          }
      }
    }
    __syncthreads();
  }
  // epilogue (C/D: col = lane&15, row = (lane>>4)*4 + q)
  #pragma unroll
  for (int m = 0; m < 2; ++m) {
    #pragma unroll
    for (int n = 0; n < 4; ++n) {
      const int col = colBase + 16 * n + lr;
      const float bv0 = bias0[col];
      const float bv1 = (MODE == 0) ? bias1[col] : 0.f;
      #pragma unroll
      for (int q = 0; q < 4; ++q) {
        const int row = rowBase + 32 * w + 16 * m + lk * 4 + q;
        const size_t o = (size_t)row * HH + col;
        if (MODE == 0) {
          float v0 = acc0[m][n][q] + bv0;
          float v1 = acc1[m][n][q] + bv1;
          unsigned int pk = (unsigned int)__half_as_ushort(__float2half(v0)) |
                            ((unsigned int)__half_as_ushort(__float2half(v1)) << 16);
          reinterpret_cast<unsigned int*>(outp)[o] = pk;
        } else {
          reinterpret_cast<__half*>(outp)[o] = __float2half(acc0[m][n][q] + bv0);
        }
      }
    }
  }
}

// ---------------------------------------------------------------------------
// Persistent scan. 256 WGs x 512 thr. WG (b,g) owns h columns [64g,64g+64).
// Wave w holds fp32 W*_h[64w..64w+64)[j] in registers as k-pair float2
// (compiler may emit v_pk_fma_f32 -> halves FMA instruction count).
//
// Handshake: single 8B tagged agent-scope relaxed store per element (as R3).
//
// Reduction: ds_add_f32 into a 4-deep rotating LDS accumulator:
//   step t: all waves atomicAdd -> accum[t&3]; wave1 zeroes accum[(t+2)&3];
//   ONE barrier; wave0 reads accum[t&3] (3 ds_read_b32) + nonlin + publish.
//   4 buffers needed: while step-t adds hit t&3, wave0 may still be reading
//   (t-1)&3 (its reduce overlaps others' next step), zero hits (t+2)&3 --
//   all distinct mod 4, and buffer reuse is barrier-separated.
// ---------------------------------------------------------------------------
__global__ __launch_bounds__(512, 2) void scan_kernel(
    const float* __restrict__ wu_h, const float* __restrict__ wr_h,
    const float* __restrict__ wc_h,
    float* __restrict__ out, const __half* __restrict__ cx,
    u64* __restrict__ hbuf) {           // [2][BB][HH] of {tag32, h_bits32}
  const int blk = blockIdx.x;
  const int b = (blk & 7) + ((blk >> 6) << 3);   // batch: 8 WGs share blk%8 (same XCD)
  const int g = (blk >> 3) & 7;                  // column-slice index
  const int tid = threadIdx.x;
  const int w = tid >> 6, l = tid & 63;
  const int j = g * 64 + l;

  // weights as k-pair float2: wu2[i] = {W[64w+2i][j], W[64w+2i+1][j]}
  f32x2 wu2[32], wr2[32], wc2[32];
  #pragma unroll
  for (int i = 0; i < 32; ++i) {
    const size_t o0 = (size_t)(w * 64 + 2 * i) * HH + j;
    const size_t o1 = o0 + HH;
    wu2[i] = f32x2{wu_h[o0], wu_h[o1]};
    wr2[i] = f32x2{wr_h[o0], wr_h[o1]};
    wc2[i] = f32x2{wc_h[o0], wc_h[o1]};
  }

  __shared__ float accum[4][3][64];
  for (int z = tid; z < 4 * 3 * 64; z += 512) ((float*)accum)[z] = 0.f;
  __syncthreads();

  float hprev = 0.f;
  unsigned int urx_c = 0;        // packed {f16 u_x, f16 r_x}, loaded 1 step ahead
  unsigned short cx_c = 0;       // f16 c_x bits, loaded 1 step ahead
  unsigned int* outu = reinterpret_cast<unsigned int*>(out);
  const unsigned short* cxu = reinterpret_cast<const unsigned short*>(cx);
  const size_t bo = (size_t)b * TT * HH;
  if (w == 0) {
    urx_c = outu[bo + j];
    cx_c = cxu[bo + j];
  }
  u64* const hb_poll = hbuf + (size_t)b * HH + w * 64 + l;   // + (t&1)*BB*HH
  u64* const hb_own  = hbuf + (size_t)b * HH + j;            // + ((t+1)&1)*BB*HH

  for (int t = 0; t < TT; ++t) {
    float hval = 0.f;
    if (t > 0) {
      u64 v;
      for (;;) {
        v = __hip_atomic_load(hb_poll + (size_t)(t & 1) * (BB * HH),
                              __ATOMIC_RELAXED, __HIP_MEMORY_SCOPE_AGENT);
        if (__all((int)((unsigned int)(v >> 32) >= (unsigned int)t))) break;
      }
      hval = __uint_as_float((unsigned int)v);
    }
    f32x2 au2 = {0.f, 0.f}, ar2 = {0.f, 0.f}, ac2 = {0.f, 0.f};
    const unsigned int hbits = __float_as_uint(hval);
    #pragma unroll
    for (int i = 0; i < 32; ++i) {
      f32x2 hp;
      hp.x = __uint_as_float(__builtin_amdgcn_readlane(hbits, 2 * i));
      hp.y = __uint_as_float(__builtin_amdgcn_readlane(hbits, 2 * i + 1));
      au2 = __builtin_elementwise_fma(hp, wu2[i], au2);
      ar2 = __builtin_elementwise_fma(hp, wr2[i], ar2);
      ac2 = __builtin_elementwise_fma(hp, wc2[i], ac2);
    }
    const int pb = t & 3;
    atomicAdd(&accum[pb][0][l], au2.x + au2.y);
    atomicAdd(&accum[pb][1][l], ar2.x + ar2.y);
    atomicAdd(&accum[pb][2][l], ac2.x + ac2.y);
    if (w == 1) {
      const int zb = (t + 2) & 3;
      accum[zb][0][l] = 0.f; accum[zb][1][l] = 0.f; accum[zb][2][l] = 0.f;
    }
    wg_barrier_lgkm();
    if (w == 0) {
      const float su = accum[pb][0][l];
      const float sr = accum[pb][1][l];
      const float sc = accum[pb][2][l];
      // prefetched one step ago -> no vmcnt stall here
      const float ux = __half2float(__ushort_as_half((unsigned short)(urx_c & 0xffffu)));
      const float rx = __half2float(__ushort_as_half((unsigned short)(urx_c >> 16)));
      const float cxf = __half2float(__ushort_as_half(cx_c));
      const float uu = fast_sigmoid(su + ux);
      const float rr = fast_sigmoid(sr + rx);
      const float ccv = fast_tanh(cxf + rr * sc);
      const float h = hprev + uu * (ccv - hprev);
      hprev = h;
      // publish FIRST (critical path): one 8B tagged store, no waits
      const u64 pv = ((u64)(unsigned int)(t + 1) << 32) | (u64)__float_as_uint(h);
      __hip_atomic_store(hb_own + (size_t)((t + 1) & 1) * (BB * HH), pv,
                         __ATOMIC_RELAXED, __HIP_MEMORY_SCOPE_AGENT);
      // non-critical: output store + next-step proj prefetch (land during next poll)
      const size_t oidx = bo + (size_t)t * HH + j;
      out[oidx] = h;
      if (t + 1 < TT) {
        urx_c = outu[oidx + HH];
        cx_c = cxu[oidx + HH];
      }
    }
    // no second barrier: rotating accum buffers remove the WAR hazard
  }
}

// ---------------------------------------------------------------------------
extern "C" void kernel_launch(void* const* d_in, const int* in_sizes, int n_in,
                              void* d_out, int out_size, void* d_ws, size_t ws_size,
                              hipStream_t stream) {
  const float* x    = (const float*)d_in[0];
  const float* wu_i = (const float*)d_in[1];
  const float* wu_h = (const float*)d_in[2];
  const float* bu   = (const float*)d_in[3];
  const float* wr_i = (const float*)d_in[4];
  const float* wr_h = (const float*)d_in[5];
  const float* br   = (const float*)d_in[6];
  const float* wc_i = (const float*)d_in[7];
  const float* wc_h = (const float*)d_in[8];
  const float* bc   = (const float*)d_in[9];
  float* out = (float*)d_out;

  // ws layout (~66.7 MiB total)
  char* ws = (char*)d_ws;
  __half* cx = (__half*)ws;                                  // 64 MiB c_x f16
  unsigned short* wuT  = (unsigned short*)(ws + (size_t)MM * HH * 2);
  unsigned short* wrT  = wuT + HH * HH;
  unsigned short* wcTh = wrT + HH * HH;
  unsigned short* wcTl = wcTh + HH * HH;
  u64* hbuf = (u64*)(wcTl + HH * HH);                        // [2][BB][HH] u64 (512 KiB)

  hipMemsetAsync(hbuf, 0, (size_t)2 * BB * HH * sizeof(u64), stream);
  wconv_kernel<<<1024, 256, 0, stream>>>(wu_i, wr_i, wc_i, wuT, wrT, wcTh, wcTl);
  proj_gemm<0><<<dim3(MM / 128, 8), 256, 0, stream>>>(x, wuT, wrT, bu, br, (void*)out);
  proj_gemm<1><<<dim3(MM / 128, 8), 256, 0, stream>>>(x, wcTh, wcTl, bc, bc, (void*)cx);

  void* args[] = { (void*)&wu_h, (void*)&wr_h, (void*)&wc_h, (void*)&out,
                   (void*)&cx, (void*)&hbuf };
  hipLaunchCooperativeKernel((void*)scan_kernel, dim3(256), dim3(512), args, 0, stream);
}

// Round 5
// 3777.564 us; speedup vs baseline: 1.6913x; 1.6913x over previous
//
#include <hip/hip_runtime.h>
#include <hip/hip_bf16.h>
#include <hip/hip_fp16.h>
#include <stdint.h>

#define BB 32
#define TT 2048
#define HH 512
#define MM (BB*TT)   // 65536 rows

typedef __attribute__((ext_vector_type(8))) short bf16x8;
typedef __attribute__((ext_vector_type(4))) float f32x4;
typedef __attribute__((ext_vector_type(2))) float f32x2;
typedef __attribute__((ext_vector_type(4))) unsigned short us4;
typedef __attribute__((ext_vector_type(8))) unsigned short us8;
typedef unsigned long long u64;

__device__ __forceinline__ unsigned short f2bf(float f) {
  __hip_bfloat16 h = __float2bfloat16(f);
  return *reinterpret_cast<unsigned short*>(&h);
}
__device__ __forceinline__ float bf2f(unsigned short u) {
  return __uint_as_float(((unsigned int)u) << 16);
}

// lgkm-only workgroup barrier: does NOT drain vmcnt (keeps prefetch/stores in flight)
__device__ __forceinline__ void wg_barrier_lgkm() {
  asm volatile("s_waitcnt lgkmcnt(0)\n\ts_barrier" ::: "memory");
}

// fast sigmoid / tanh (v_exp + v_rcp; |err| ~1e-6, fine vs 0.02 budget)
__device__ __forceinline__ float fast_sigmoid(float x) {
  float e = __expf(-x);                       // large +x -> e->0 -> 1; large -x -> inf -> rcp -> 0
  return __builtin_amdgcn_rcpf(1.f + e);
}
__device__ __forceinline__ float fast_tanh(float x) {
  float xc = fminf(fmaxf(x, -15.f), 15.f);    // avoid inf/inf
  float e2 = __expf(2.f * xc);
  return (e2 - 1.f) * __builtin_amdgcn_rcpf(e2 + 1.f);
}

// ---------------------------------------------------------------------------
// Weight convert + transpose: W[k][n] fp32 -> WT[n][k] bf16 (and hi/lo for wc_i)
// ---------------------------------------------------------------------------
__global__ void wconv_kernel(const float* __restrict__ wu, const float* __restrict__ wr,
                             const float* __restrict__ wc,
                             unsigned short* __restrict__ wuT, unsigned short* __restrict__ wrT,
                             unsigned short* __restrict__ wcTh, unsigned short* __restrict__ wcTl) {
  int idx = blockIdx.x * 256 + threadIdx.x;      // 0..262143
  int n = idx >> 9, k = idx & 511;
  int src = k * HH + n;
  wuT[idx] = f2bf(wu[src]);
  wrT[idx] = f2bf(wr[src]);
  float v = wc[src];
  unsigned short hi = f2bf(v);
  wcTh[idx] = hi;
  wcTl[idx] = f2bf(v - bf2f(hi));
}

// ---------------------------------------------------------------------------
// Projection GEMM.  A = x (M x 512 fp32, converted to bf16 tiles on the fly),
// B*T stored transposed [N][K] bf16.  BM=128 BN=64 BK=64, 256 thr / 4 waves.
// MODE 0: out = pack(f16(A@B0 + bias0), f16(A@B1 + bias1)) as u32 -> d_out
// MODE 1: out = f16(Ah@B0h + Ah@B0l + Al@B0h + bias0)             -> ws (c_x)
// ---------------------------------------------------------------------------
template<int MODE>
__global__ __launch_bounds__(256) void proj_gemm(
    const float* __restrict__ X,
    const unsigned short* __restrict__ B0T,
    const unsigned short* __restrict__ B1T,
    const float* __restrict__ bias0,
    const float* __restrict__ bias1,
    void* __restrict__ outp) {
  __shared__ __attribute__((aligned(16))) unsigned short Ah[128][72];
  __shared__ __attribute__((aligned(16))) unsigned short Al[128][72];
  __shared__ __attribute__((aligned(16))) unsigned short Bs0[64][72];
  __shared__ __attribute__((aligned(16))) unsigned short Bs1[64][72];
  const int tid = threadIdx.x;
  const int w = tid >> 6, l = tid & 63;
  const int lr = l & 15, lk = l >> 4;
  const int rowBase = blockIdx.x * 128;
  const int colBase = blockIdx.y * 64;

  f32x4 acc0[2][4], acc1[2][4];
  const f32x4 zero = {0.f, 0.f, 0.f, 0.f};
  #pragma unroll
  for (int m = 0; m < 2; ++m)
    #pragma unroll
    for (int n = 0; n < 4; ++n) { acc0[m][n] = zero; acc1[m][n] = zero; }

  for (int kt = 0; kt < 8; ++kt) {
    // stage A (fp32 -> bf16, hi/lo for MODE 1)
    #pragma unroll
    for (int i = 0; i < 8; ++i) {
      int idx = tid + 256 * i;
      int r = idx >> 4, c4 = idx & 15;
      float4 v = *reinterpret_cast<const float4*>(
          X + (size_t)(rowBase + r) * HH + kt * 64 + c4 * 4);
      us4 hv;
      hv.x = f2bf(v.x); hv.y = f2bf(v.y); hv.z = f2bf(v.z); hv.w = f2bf(v.w);
      *reinterpret_cast<us4*>(&Ah[r][c4 * 4]) = hv;
      if (MODE == 1) {
        us4 lv;
        lv.x = f2bf(v.x - bf2f(hv.x)); lv.y = f2bf(v.y - bf2f(hv.y));
        lv.z = f2bf(v.z - bf2f(hv.z)); lv.w = f2bf(v.w - bf2f(hv.w));
        *reinterpret_cast<us4*>(&Al[r][c4 * 4]) = lv;
      }
    }
    // stage B (already bf16, [n][k] layout)
    #pragma unroll
    for (int i = 0; i < 2; ++i) {
      int idx = tid + 256 * i;
      int n = idx >> 3, k8 = idx & 7;
      const size_t go = (size_t)(colBase + n) * HH + kt * 64 + k8 * 8;
      *reinterpret_cast<us8*>(&Bs0[n][k8 * 8]) = *reinterpret_cast<const us8*>(B0T + go);
      *reinterpret_cast<us8*>(&Bs1[n][k8 * 8]) = *reinterpret_cast<const us8*>(B1T + go);
    }
    __syncthreads();
    #pragma unroll
    for (int ks = 0; ks < 2; ++ks) {
      const int k0 = ks * 32 + lk * 8;
      bf16x8 a[2], b0[4], b1[4];
      #pragma unroll
      for (int m = 0; m < 2; ++m)
        a[m] = *reinterpret_cast<const bf16x8*>(&Ah[32 * w + 16 * m + lr][k0]);
      #pragma unroll
      for (int n = 0; n < 4; ++n) {
        b0[n] = *reinterpret_cast<const bf16x8*>(&Bs0[16 * n + lr][k0]);
        b1[n] = *reinterpret_cast<const bf16x8*>(&Bs1[16 * n + lr][k0]);
      }
      if (MODE == 1) {
        bf16x8 al[2];
        #pragma unroll
        for (int m = 0; m < 2; ++m)
          al[m] = *reinterpret_cast<const bf16x8*>(&Al[32 * w + 16 * m + lr][k0]);
        #pragma unroll
        for (int m = 0; m < 2; ++m)
          #pragma unroll
          for (int n = 0; n < 4; ++n) {
            acc0[m][n] = __builtin_amdgcn_mfma_f32_16x16x32_bf16(a[m],  b0[n], acc0[m][n], 0, 0, 0);
            acc0[m][n] = __builtin_amdgcn_mfma_f32_16x16x32_bf16(a[m],  b1[n], acc0[m][n], 0, 0, 0);
            acc0[m][n] = __builtin_amdgcn_mfma_f32_16x16x32_bf16(al[m], b0[n], acc0[m][n], 0, 0, 0);
          }
      } else {
        #pragma unroll
        for (int m = 0; m < 2; ++m)
          #pragma unroll
          for (int n = 0; n < 4; ++n) {
            acc0[m][n] = __builtin_amdgcn_mfma_f32_16x16x32_bf16(a[m], b0[n], acc0[m][n], 0, 0, 0);
            acc1[m][n] = __builtin_amdgcn_mfma_f32_16x16x32_bf16(a[m], b1[n], acc1[m][n], 0, 0, 0);
          }
      }
    }
    __syncthreads();
  }
  // epilogue (C/D: col = lane&15, row = (lane>>4)*4 + q)
  #pragma unroll
  for (int m = 0; m < 2; ++m) {
    #pragma unroll
    for (int n = 0; n < 4; ++n) {
      const int col = colBase + 16 * n + lr;
      const float bv0 = bias0[col];
      const float bv1 = (MODE == 0) ? bias1[col] : 0.f;
      #pragma unroll
      for (int q = 0; q < 4; ++q) {
        const int row = rowBase + 32 * w + 16 * m + lk * 4 + q;
        const size_t o = (size_t)row * HH + col;
        if (MODE == 0) {
          float v0 = acc0[m][n][q] + bv0;
          float v1 = acc1[m][n][q] + bv1;
          unsigned int pk = (unsigned int)__half_as_ushort(__float2half(v0)) |
                            ((unsigned int)__half_as_ushort(__float2half(v1)) << 16);
          reinterpret_cast<unsigned int*>(outp)[o] = pk;
        } else {
          reinterpret_cast<__half*>(outp)[o] = __float2half(acc0[m][n][q] + bv0);
        }
      }
    }
  }
}

// ---------------------------------------------------------------------------
// Persistent scan. 256 WGs x 512 thr. WG (b,g) owns h columns [64g,64g+64).
// Wave w holds fp32 W*_h[64w..64w+64)[j] as k-pair float2 (v_pk_fma_f32).
//
// Handshake: single 8B tagged agent-scope relaxed store per element (R3).
//
// Reduction (R4 LDS-atomics regressed; reverted): conflict-free parts array
// parts[2][8][3][64], DOUBLE-buffered so the second barrier stays removed:
//   step t: all waves write parts[t&1][w][*][l]; ONE lgkm barrier;
//   wave0 reads 24 floats, nonlin, publish.
// Overwrite safety: buffer t&1 is rewritten at t+2, only after waves pass
// barrier(t+1); wave0 reaches barrier(t+1) strictly after reduce(t) reads.
// ---------------------------------------------------------------------------
__global__ __launch_bounds__(512, 2) void scan_kernel(
    const float* __restrict__ wu_h, const float* __restrict__ wr_h,
    const float* __restrict__ wc_h,
    float* __restrict__ out, const __half* __restrict__ cx,
    u64* __restrict__ hbuf) {           // [2][BB][HH] of {tag32, h_bits32}
  const int blk = blockIdx.x;
  const int b = (blk & 7) + ((blk >> 6) << 3);   // batch: 8 WGs share blk%8 (same XCD)
  const int g = (blk >> 3) & 7;                  // column-slice index
  const int tid = threadIdx.x;
  const int w = tid >> 6, l = tid & 63;
  const int j = g * 64 + l;

  // weights as k-pair float2: wu2[i] = {W[64w+2i][j], W[64w+2i+1][j]}
  f32x2 wu2[32], wr2[32], wc2[32];
  #pragma unroll
  for (int i = 0; i < 32; ++i) {
    const size_t o0 = (size_t)(w * 64 + 2 * i) * HH + j;
    const size_t o1 = o0 + HH;
    wu2[i] = f32x2{wu_h[o0], wu_h[o1]};
    wr2[i] = f32x2{wr_h[o0], wr_h[o1]};
    wc2[i] = f32x2{wc_h[o0], wc_h[o1]};
  }

  __shared__ float parts[2][8][3][64];

  float hprev = 0.f;
  unsigned int urx_c = 0;        // packed {f16 u_x, f16 r_x}, loaded 1 step ahead
  unsigned short cx_c = 0;       // f16 c_x bits, loaded 1 step ahead
  unsigned int* outu = reinterpret_cast<unsigned int*>(out);
  const unsigned short* cxu = reinterpret_cast<const unsigned short*>(cx);
  const size_t bo = (size_t)b * TT * HH;
  if (w == 0) {
    urx_c = outu[bo + j];
    cx_c = cxu[bo + j];
  }
  u64* const hb_poll = hbuf + (size_t)b * HH + w * 64 + l;   // + (t&1)*BB*HH
  u64* const hb_own  = hbuf + (size_t)b * HH + j;            // + ((t+1)&1)*BB*HH

  for (int t = 0; t < TT; ++t) {
    float hval = 0.f;
    if (t > 0) {
      u64 v;
      for (;;) {
        v = __hip_atomic_load(hb_poll + (size_t)(t & 1) * (BB * HH),
                              __ATOMIC_RELAXED, __HIP_MEMORY_SCOPE_AGENT);
        if (__all((int)((unsigned int)(v >> 32) >= (unsigned int)t))) break;
      }
      hval = __uint_as_float((unsigned int)v);
    }
    f32x2 au2 = {0.f, 0.f}, ar2 = {0.f, 0.f}, ac2 = {0.f, 0.f};
    const unsigned int hbits = __float_as_uint(hval);
    #pragma unroll
    for (int i = 0; i < 32; ++i) {
      f32x2 hp;
      hp.x = __uint_as_float(__builtin_amdgcn_readlane(hbits, 2 * i));
      hp.y = __uint_as_float(__builtin_amdgcn_readlane(hbits, 2 * i + 1));
      au2 = __builtin_elementwise_fma(hp, wu2[i], au2);
      ar2 = __builtin_elementwise_fma(hp, wr2[i], ar2);
      ac2 = __builtin_elementwise_fma(hp, wc2[i], ac2);
    }
    const int pb = t & 1;
    parts[pb][w][0][l] = au2.x + au2.y;
    parts[pb][w][1][l] = ar2.x + ar2.y;
    parts[pb][w][2][l] = ac2.x + ac2.y;
    wg_barrier_lgkm();
    if (w == 0) {
      float su = 0.f, sr = 0.f, sc = 0.f;
      #pragma unroll
      for (int ww = 0; ww < 8; ++ww) {
        su += parts[pb][ww][0][l];
        sr += parts[pb][ww][1][l];
        sc += parts[pb][ww][2][l];
      }
      // prefetched one step ago -> no vmcnt stall here
      const float ux = __half2float(__ushort_as_half((unsigned short)(urx_c & 0xffffu)));
      const float rx = __half2float(__ushort_as_half((unsigned short)(urx_c >> 16)));
      const float cxf = __half2float(__ushort_as_half(cx_c));
      const float uu = fast_sigmoid(su + ux);
      const float rr = fast_sigmoid(sr + rx);
      const float ccv = fast_tanh(cxf + rr * sc);
      const float h = hprev + uu * (ccv - hprev);
      hprev = h;
      // publish FIRST (critical path): one 8B tagged store, no waits
      const u64 pv = ((u64)(unsigned int)(t + 1) << 32) | (u64)__float_as_uint(h);
      __hip_atomic_store(hb_own + (size_t)((t + 1) & 1) * (BB * HH), pv,
                         __ATOMIC_RELAXED, __HIP_MEMORY_SCOPE_AGENT);
      // non-critical: output store + next-step proj prefetch (land during next poll)
      const size_t oidx = bo + (size_t)t * HH + j;
      out[oidx] = h;
      if (t + 1 < TT) {
        urx_c = outu[oidx + HH];
        cx_c = cxu[oidx + HH];
      }
    }
    // no second barrier: double-buffered parts removes the WAR hazard
  }
}

// ---------------------------------------------------------------------------
extern "C" void kernel_launch(void* const* d_in, const int* in_sizes, int n_in,
                              void* d_out, int out_size, void* d_ws, size_t ws_size,
                              hipStream_t stream) {
  const float* x    = (const float*)d_in[0];
  const float* wu_i = (const float*)d_in[1];
  const float* wu_h = (const float*)d_in[2];
  const float* bu   = (const float*)d_in[3];
  const float* wr_i = (const float*)d_in[4];
  const float* wr_h = (const float*)d_in[5];
  const float* br   = (const float*)d_in[6];
  const float* wc_i = (const float*)d_in[7];
  const float* wc_h = (const float*)d_in[8];
  const float* bc   = (const float*)d_in[9];
  float* out = (float*)d_out;

  // ws layout (~66.7 MiB total)
  char* ws = (char*)d_ws;
  __half* cx = (__half*)ws;                                  // 64 MiB c_x f16
  unsigned short* wuT  = (unsigned short*)(ws + (size_t)MM * HH * 2);
  unsigned short* wrT  = wuT + HH * HH;
  unsigned short* wcTh = wrT + HH * HH;
  unsigned short* wcTl = wcTh + HH * HH;
  u64* hbuf = (u64*)(wcTl + HH * HH);                        // [2][BB][HH] u64 (512 KiB)

  hipMemsetAsync(hbuf, 0, (size_t)2 * BB * HH * sizeof(u64), stream);
  wconv_kernel<<<1024, 256, 0, stream>>>(wu_i, wr_i, wc_i, wuT, wrT, wcTh, wcTl);
  proj_gemm<0><<<dim3(MM / 128, 8), 256, 0, stream>>>(x, wuT, wrT, bu, br, (void*)out);
  proj_gemm<1><<<dim3(MM / 128, 8), 256, 0, stream>>>(x, wcTh, wcTl, bc, bc, (void*)cx);

  void* args[] = { (void*)&wu_h, (void*)&wr_h, (void*)&wc_h, (void*)&out,
                   (void*)&cx, (void*)&hbuf };
  hipLaunchCooperativeKernel((void*)scan_kernel, dim3(256), dim3(512), args, 0, stream);
}